// Round 1
// baseline (515.646 us; speedup 1.0000x reference)
//
#include <hip/hip_runtime.h>
#include <hip/hip_bf16.h>
#include <math.h>

// Problem constants
#define BATCH 8
#define SEQ   2048
#define CH    512
#define ROWS  (BATCH * SEQ)   // 16384
#define INVSQ 0.044194173824159216f  // 1/sqrt(512)

// Tile config
#define BM 128
#define BN 128
#define BK 32
#define LDK 40   // padded leading dim (bf16 elems) -> 80B rows, 16B-aligned

typedef __attribute__((ext_vector_type(8))) __bf16 bf16x8;
typedef __attribute__((ext_vector_type(4))) float f32x4;

__device__ inline unsigned short f2bf(float f) {
    unsigned u = __builtin_bit_cast(unsigned, f);
    u += 0x7fffu + ((u >> 16) & 1u);   // round-to-nearest-even
    return (unsigned short)(u >> 16);
}
__device__ inline float bf2f(unsigned short s) {
    unsigned u = ((unsigned)s) << 16;
    return __builtin_bit_cast(float, u);
}

// ---------------------------------------------------------------------------
// Kernel 1: projection GEMM  out[M=16384, N=512] = bf16(x @ W + b)
// x fp32 [16384,512], W fp32 [512,512] (k-major rows), b fp32 [512]
// grid: (N/128=4, M/128=128), block 256 (4 waves, 2x2 of 64x64)
// ---------------------------------------------------------------------------
__global__ __launch_bounds__(256) void qkv_kernel(
    const float* __restrict__ x, const float* __restrict__ W,
    const float* __restrict__ bias, unsigned short* __restrict__ out)
{
    __shared__ unsigned short As[BM * LDK];
    __shared__ unsigned short Bs[BN * LDK];
    const int n0 = blockIdx.x * BN;
    const int m0 = blockIdx.y * BM;
    const int tid = threadIdx.x;
    const int lane = tid & 63, wave = tid >> 6;
    const int wm = (wave >> 1) * 64, wn = (wave & 1) * 64;
    const int quad = lane >> 4, l16 = lane & 15;

    f32x4 acc[4][4] = {};
    for (int kk = 0; kk < CH; kk += BK) {
        // A tile: 128 rows x 32 k, fp32 -> bf16. 1024 float4 slots / 256 thr = 4
#pragma unroll
        for (int i = 0; i < 4; ++i) {
            int slot = tid + i * 256;
            int row = slot >> 3, k4 = (slot & 7) << 2;
            float4 v = *(const float4*)(x + (size_t)(m0 + row) * CH + kk + k4);
            unsigned short* dst = As + row * LDK + k4;
            dst[0] = f2bf(v.x); dst[1] = f2bf(v.y); dst[2] = f2bf(v.z); dst[3] = f2bf(v.w);
        }
        // B tile: W[kk+kr][n0+nc] -> Bs[nc][kr] (transpose into n-major)
#pragma unroll
        for (int i = 0; i < 4; ++i) {
            int slot = tid + i * 256;
            int kr = slot >> 5, nc4 = (slot & 31) << 2;
            float4 v = *(const float4*)(W + (size_t)(kk + kr) * CH + n0 + nc4);
            Bs[(nc4 + 0) * LDK + kr] = f2bf(v.x);
            Bs[(nc4 + 1) * LDK + kr] = f2bf(v.y);
            Bs[(nc4 + 2) * LDK + kr] = f2bf(v.z);
            Bs[(nc4 + 3) * LDK + kr] = f2bf(v.w);
        }
        __syncthreads();
        bf16x8 a[4], b[4];
#pragma unroll
        for (int r = 0; r < 4; ++r)
            a[r] = *(const bf16x8*)(As + (wm + r * 16 + l16) * LDK + quad * 8);
#pragma unroll
        for (int c = 0; c < 4; ++c)
            b[c] = *(const bf16x8*)(Bs + (wn + c * 16 + l16) * LDK + quad * 8);
#pragma unroll
        for (int r = 0; r < 4; ++r)
#pragma unroll
            for (int c = 0; c < 4; ++c)
                acc[r][c] = __builtin_amdgcn_mfma_f32_16x16x32_bf16(a[r], b[c], acc[r][c], 0, 0, 0);
        __syncthreads();
    }
#pragma unroll
    for (int r = 0; r < 4; ++r)
#pragma unroll
        for (int c = 0; c < 4; ++c) {
            int col = n0 + wn + c * 16 + l16;
            float bv = bias[col];
#pragma unroll
            for (int reg = 0; reg < 4; ++reg) {
                int row = m0 + wm + r * 16 + quad * 4 + reg;
                out[(size_t)row * CH + col] = f2bf(acc[r][c][reg] + bv);
            }
        }
}

// ---------------------------------------------------------------------------
// Kernel 2: E[b,t,s] = exp(q[b,t,:]·k[b,s,:] * INVSQ) for s<=t else 0 (bf16),
// and Z[b,s] += column sums. grid: (st=16, tt=16, b=8); early-out st>tt.
// ---------------------------------------------------------------------------
__global__ __launch_bounds__(256) void logits_kernel(
    const unsigned short* __restrict__ qb, const unsigned short* __restrict__ kb,
    unsigned short* __restrict__ E, float* __restrict__ Z)
{
    const int st = blockIdx.x, tt = blockIdx.y, b = blockIdx.z;
    if (st > tt) return;
    __shared__ unsigned short As[BM * LDK];
    __shared__ unsigned short Bs[BN * LDK];
    __shared__ float colsum[BN];
    const int m0 = tt * BM;   // t rows
    const int n0 = st * BN;   // s cols
    const int tid = threadIdx.x;
    const int lane = tid & 63, wave = tid >> 6;
    const int wm = (wave >> 1) * 64, wn = (wave & 1) * 64;
    const int quad = lane >> 4, l16 = lane & 15;
    const unsigned short* q = qb + (size_t)b * SEQ * CH;
    const unsigned short* k = kb + (size_t)b * SEQ * CH;

    f32x4 acc[4][4] = {};
    for (int kk = 0; kk < CH; kk += BK) {
        // both tiles: 128 rows x 32 k bf16, contiguous k -> uint4 copies (2/thr)
#pragma unroll
        for (int i = 0; i < 2; ++i) {
            int slot = tid + i * 256;
            int row = slot >> 2, k8 = (slot & 3) << 3;
            *(uint4*)(As + row * LDK + k8) = *(const uint4*)(q + (size_t)(m0 + row) * CH + kk + k8);
        }
#pragma unroll
        for (int i = 0; i < 2; ++i) {
            int slot = tid + i * 256;
            int row = slot >> 2, k8 = (slot & 3) << 3;
            *(uint4*)(Bs + row * LDK + k8) = *(const uint4*)(k + (size_t)(n0 + row) * CH + kk + k8);
        }
        __syncthreads();
        bf16x8 a[4], bfr[4];
#pragma unroll
        for (int r = 0; r < 4; ++r)
            a[r] = *(const bf16x8*)(As + (wm + r * 16 + l16) * LDK + quad * 8);
#pragma unroll
        for (int c = 0; c < 4; ++c)
            bfr[c] = *(const bf16x8*)(Bs + (wn + c * 16 + l16) * LDK + quad * 8);
#pragma unroll
        for (int r = 0; r < 4; ++r)
#pragma unroll
            for (int c = 0; c < 4; ++c)
                acc[r][c] = __builtin_amdgcn_mfma_f32_16x16x32_bf16(a[r], bfr[c], acc[r][c], 0, 0, 0);
        __syncthreads();
    }
    if (tid < BN) colsum[tid] = 0.f;
    __syncthreads();
#pragma unroll
    for (int r = 0; r < 4; ++r)
#pragma unroll
        for (int c = 0; c < 4; ++c) {
            int cl = wn + c * 16 + l16;
            int s = n0 + cl;
            float csum = 0.f;
#pragma unroll
            for (int reg = 0; reg < 4; ++reg) {
                int t = m0 + wm + r * 16 + quad * 4 + reg;
                float e = (s <= t) ? __expf(acc[r][c][reg] * INVSQ) : 0.f;
                csum += e;
                E[((size_t)b * SEQ + t) * SEQ + s] = f2bf(e);
            }
            atomicAdd(&colsum[cl], csum);
        }
    __syncthreads();
    if (tid < BN) atomicAdd(&Z[b * SEQ + n0 + tid], colsum[tid]);
}

// ---------------------------------------------------------------------------
// Kernel 3a: zero Z. Kernel 3b: vb[row,:] *= 1/Z[row] in place.
// ---------------------------------------------------------------------------
__global__ __launch_bounds__(256) void zero_kernel(float* __restrict__ Z) {
    int i = blockIdx.x * 256 + threadIdx.x;
    if (i < ROWS) Z[i] = 0.f;
}
__global__ __launch_bounds__(256) void scale_v_kernel(
    unsigned short* __restrict__ vb, const float* __restrict__ Z)
{
    int row = blockIdx.x;
    float inv = 1.0f / Z[row];
    unsigned short* p = vb + (size_t)row * CH;
    int i = threadIdx.x;
#pragma unroll
    for (int j = 0; j < 2; ++j) {
        int idx = i + j * 256;
        p[idx] = f2bf(bf2f(p[idx]) * inv);
    }
}

// ---------------------------------------------------------------------------
// Kernel 4: read = E @ V_scaled (causal K-loop), fp32 -> out[:, :, 512:1024]
// grid: (nt=4, tt=16, b=8)
// ---------------------------------------------------------------------------
__global__ __launch_bounds__(256) void read_kernel(
    const unsigned short* __restrict__ E, const unsigned short* __restrict__ vb,
    float* __restrict__ out)
{
    __shared__ unsigned short As[BM * LDK];
    __shared__ unsigned short Bs[BN * LDK];
    const int n0 = blockIdx.x * BN;
    const int m0 = blockIdx.y * BM;
    const int b = blockIdx.z;
    const int tid = threadIdx.x;
    const int lane = tid & 63, wave = tid >> 6;
    const int wm = (wave >> 1) * 64, wn = (wave & 1) * 64;
    const int quad = lane >> 4, l16 = lane & 15;
    const unsigned short* Eb = E + (size_t)b * SEQ * SEQ;
    const unsigned short* Vb = vb + (size_t)b * SEQ * CH;
    const int Kmax = (blockIdx.y + 1) * BM;   // causal: s <= tile's max t

    f32x4 acc[4][4] = {};
    for (int kk = 0; kk < Kmax; kk += BK) {
        // A tile from E: 128 t-rows x 32 s, contiguous
#pragma unroll
        for (int i = 0; i < 2; ++i) {
            int slot = tid + i * 256;
            int row = slot >> 2, k8 = (slot & 3) << 3;
            *(uint4*)(As + row * LDK + k8) = *(const uint4*)(Eb + (size_t)(m0 + row) * SEQ + kk + k8);
        }
        // B tile from V: [s][v] -> Bs[v][s] transpose
#pragma unroll
        for (int i = 0; i < 2; ++i) {
            int slot = tid + i * 256;
            int kr = slot >> 4, nc8 = (slot & 15) << 3;
            uint4 v = *(const uint4*)(Vb + (size_t)(kk + kr) * CH + n0 + nc8);
            const unsigned short* pv = (const unsigned short*)&v;
#pragma unroll
            for (int j = 0; j < 8; ++j) Bs[(nc8 + j) * LDK + kr] = pv[j];
        }
        __syncthreads();
        bf16x8 a[4], bfr[4];
#pragma unroll
        for (int r = 0; r < 4; ++r)
            a[r] = *(const bf16x8*)(As + (wm + r * 16 + l16) * LDK + quad * 8);
#pragma unroll
        for (int c = 0; c < 4; ++c)
            bfr[c] = *(const bf16x8*)(Bs + (wn + c * 16 + l16) * LDK + quad * 8);
#pragma unroll
        for (int r = 0; r < 4; ++r)
#pragma unroll
            for (int c = 0; c < 4; ++c)
                acc[r][c] = __builtin_amdgcn_mfma_f32_16x16x32_bf16(a[r], bfr[c], acc[r][c], 0, 0, 0);
        __syncthreads();
    }
    float* ob = out + ((size_t)b * SEQ + m0) * 1024 + 512 + n0;
#pragma unroll
    for (int r = 0; r < 4; ++r)
#pragma unroll
        for (int c = 0; c < 4; ++c)
#pragma unroll
            for (int reg = 0; reg < 4; ++reg)
                ob[(size_t)(wm + r * 16 + quad * 4 + reg) * 1024 + wn + c * 16 + l16] = acc[r][c][reg];
}

// ---------------------------------------------------------------------------
// Kernel 5: copy x into out[:, :, 0:512]
// ---------------------------------------------------------------------------
__global__ __launch_bounds__(256) void copy_x_kernel(
    const float* __restrict__ x, float* __restrict__ out)
{
    int g = blockIdx.x * 256 + threadIdx.x;      // 0..2097151 float4s
    int row = g >> 7;
    int c4 = (g & 127) << 2;
    *(float4*)(out + (size_t)row * 1024 + c4) = *(const float4*)(x + (size_t)row * CH + c4);
}

extern "C" void kernel_launch(void* const* d_in, const int* in_sizes, int n_in,
                              void* d_out, int out_size, void* d_ws, size_t ws_size,
                              hipStream_t stream) {
    const float* x  = (const float*)d_in[0];
    const float* Wq = (const float*)d_in[1];
    const float* bq = (const float*)d_in[2];
    const float* Wk = (const float*)d_in[3];
    const float* bk = (const float*)d_in[4];
    const float* Wv = (const float*)d_in[5];
    const float* bv = (const float*)d_in[6];
    float* out = (float*)d_out;

    char* ws = (char*)d_ws;
    const size_t QKV_BYTES = (size_t)ROWS * CH * 2;        // 16,777,216
    unsigned short* qb = (unsigned short*)ws;
    unsigned short* kb = (unsigned short*)(ws + QKV_BYTES);
    unsigned short* vb = (unsigned short*)(ws + 2 * QKV_BYTES);
    unsigned short* E  = (unsigned short*)(ws + 3 * QKV_BYTES);   // 67,108,864
    float* Z = (float*)(ws + 3 * QKV_BYTES + (size_t)BATCH * SEQ * SEQ * 2);

    dim3 blk(256);
    zero_kernel<<<dim3((ROWS + 255) / 256), blk, 0, stream>>>(Z);
    qkv_kernel<<<dim3(4, 128), blk, 0, stream>>>(x, Wq, bq, qb);
    qkv_kernel<<<dim3(4, 128), blk, 0, stream>>>(x, Wk, bk, kb);
    qkv_kernel<<<dim3(4, 128), blk, 0, stream>>>(x, Wv, bv, vb);
    logits_kernel<<<dim3(16, 16, 8), blk, 0, stream>>>(qb, kb, E, Z);
    scale_v_kernel<<<dim3(ROWS), blk, 0, stream>>>(vb, Z);
    read_kernel<<<dim3(4, 16, 8), blk, 0, stream>>>(E, vb, out);
    copy_x_kernel<<<dim3(8192), blk, 0, stream>>>(x, out);
}

// Round 2
// 323.283 us; speedup vs baseline: 1.5950x; 1.5950x over previous
//
#include <hip/hip_runtime.h>
#include <hip/hip_bf16.h>
#include <math.h>

// Problem constants
#define BATCH 8
#define SEQ   2048
#define CH    512
#define ROWS  (BATCH * SEQ)   // 16384
#define INVSQ 0.044194173824159216f  // 1/sqrt(512)

// Tile config
#define BM 128
#define BN 128
#define BK 32
#define LDK 40   // padded leading dim (bf16 elems) -> 80B rows, 16B-aligned
#define TP 68    // transpose-tile pitch (shorts): 4*68 mod 32 = 16 -> 2-way (free), 136B row base 8B-aligned

typedef __attribute__((ext_vector_type(8))) __bf16 bf16x8;
typedef __attribute__((ext_vector_type(4))) float f32x4;

__device__ inline unsigned short f2bf(float f) {
    unsigned u = __builtin_bit_cast(unsigned, f);
    u += 0x7fffu + ((u >> 16) & 1u);   // round-to-nearest-even
    return (unsigned short)(u >> 16);
}
__device__ inline float bf2f(unsigned short s) {
    unsigned u = ((unsigned)s) << 16;
    return __builtin_bit_cast(float, u);
}

// ---------------------------------------------------------------------------
// convert_x: x fp32 [16384,512] -> xb bf16. 8 elems/thread, 4096 blocks.
// ---------------------------------------------------------------------------
__global__ __launch_bounds__(256) void convert_x_kernel(
    const float* __restrict__ x, unsigned short* __restrict__ xb)
{
    size_t base = ((size_t)blockIdx.x * 256 + threadIdx.x) * 8;
    float4 v0 = *(const float4*)(x + base);
    float4 v1 = *(const float4*)(x + base + 4);
    unsigned short t[8];
    t[0] = f2bf(v0.x); t[1] = f2bf(v0.y); t[2] = f2bf(v0.z); t[3] = f2bf(v0.w);
    t[4] = f2bf(v1.x); t[5] = f2bf(v1.y); t[6] = f2bf(v1.z); t[7] = f2bf(v1.w);
    *(uint4*)(xb + base) = *(uint4*)t;
}

// ---------------------------------------------------------------------------
// transpose_w: W fp32 [512 k][512 n] -> Wt bf16 [3][512 n][512 k]
// grid (k-tiles=8, n-tiles=8, w=3), 64x64 tiles.
// ---------------------------------------------------------------------------
__global__ __launch_bounds__(256) void transpose_w_kernel(
    const float* __restrict__ Wq, const float* __restrict__ Wk,
    const float* __restrict__ Wv, unsigned short* __restrict__ Wt)
{
    __shared__ unsigned short T[64 * TP];
    const int k0 = blockIdx.x * 64, n0 = blockIdx.y * 64, w = blockIdx.z;
    const float* W = (w == 0) ? Wq : (w == 1) ? Wk : Wv;
    const int tid = threadIdx.x;
#pragma unroll
    for (int i = 0; i < 2; ++i) {
        int slot = tid + i * 256;
        int kr = slot >> 3, c8 = (slot & 7) << 3;
        float4 a = *(const float4*)(W + (size_t)(k0 + kr) * CH + n0 + c8);
        float4 b = *(const float4*)(W + (size_t)(k0 + kr) * CH + n0 + c8 + 4);
        T[(c8 + 0) * TP + kr] = f2bf(a.x); T[(c8 + 1) * TP + kr] = f2bf(a.y);
        T[(c8 + 2) * TP + kr] = f2bf(a.z); T[(c8 + 3) * TP + kr] = f2bf(a.w);
        T[(c8 + 4) * TP + kr] = f2bf(b.x); T[(c8 + 5) * TP + kr] = f2bf(b.y);
        T[(c8 + 6) * TP + kr] = f2bf(b.z); T[(c8 + 7) * TP + kr] = f2bf(b.w);
    }
    __syncthreads();
#pragma unroll
    for (int i = 0; i < 2; ++i) {
        int slot = tid + i * 256;
        int nr = slot >> 3, k8 = (slot & 7) << 3;
        uint2 lo = *(const uint2*)(T + nr * TP + k8);
        uint2 hi = *(const uint2*)(T + nr * TP + k8 + 4);
        uint4 u; u.x = lo.x; u.y = lo.y; u.z = hi.x; u.w = hi.y;
        *(uint4*)(Wt + ((size_t)w * CH + n0 + nr) * CH + k0 + k8) = u;
    }
}

// ---------------------------------------------------------------------------
// transpose_v: vb bf16 [b][s][v] -> Vt bf16 [b][v][s], scaled by 1/Z[b][s].
// grid (s-tiles=32, v-tiles=8, b=8), 64x64 tiles.
// ---------------------------------------------------------------------------
__global__ __launch_bounds__(256) void transpose_v_kernel(
    const unsigned short* __restrict__ vb, const float* __restrict__ Z,
    unsigned short* __restrict__ Vt)
{
    __shared__ unsigned short T[64 * TP];
    const int s0 = blockIdx.x * 64, v0 = blockIdx.y * 64, b = blockIdx.z;
    const int tid = threadIdx.x;
#pragma unroll
    for (int i = 0; i < 2; ++i) {
        int slot = tid + i * 256;
        int sr = slot >> 3, c8 = (slot & 7) << 3;
        float inv = 1.0f / Z[b * SEQ + s0 + sr];
        uint4 raw = *(const uint4*)(vb + ((size_t)b * SEQ + s0 + sr) * CH + v0 + c8);
        const unsigned short* p = (const unsigned short*)&raw;
#pragma unroll
        for (int j = 0; j < 8; ++j)
            T[(c8 + j) * TP + sr] = f2bf(bf2f(p[j]) * inv);
    }
    __syncthreads();
#pragma unroll
    for (int i = 0; i < 2; ++i) {
        int slot = tid + i * 256;
        int vr = slot >> 3, s8 = (slot & 7) << 3;
        uint2 lo = *(const uint2*)(T + vr * TP + s8);
        uint2 hi = *(const uint2*)(T + vr * TP + s8 + 4);
        uint4 u; u.x = lo.x; u.y = lo.y; u.z = hi.x; u.w = hi.y;
        *(uint4*)(Vt + ((size_t)b * CH + v0 + vr) * SEQ + s0 + s8) = u;
    }
}

// ---------------------------------------------------------------------------
// qkv GEMM: out[16384,512] = bf16(xb @ Wt^T + b) — all-bf16, contiguous staging.
// xb [M][K] k-major, Wt [N][K] k-major. grid (4, 128).
// ---------------------------------------------------------------------------
__global__ __launch_bounds__(256) void qkv_kernel(
    const unsigned short* __restrict__ xb, const unsigned short* __restrict__ Wt,
    const float* __restrict__ bias, unsigned short* __restrict__ out)
{
    __shared__ unsigned short As[BM * LDK];
    __shared__ unsigned short Bs[BN * LDK];
    const int n0 = blockIdx.x * BN;
    const int m0 = blockIdx.y * BM;
    const int tid = threadIdx.x;
    const int lane = tid & 63, wave = tid >> 6;
    const int wm = (wave >> 1) * 64, wn = (wave & 1) * 64;
    const int quad = lane >> 4, l16 = lane & 15;

    f32x4 acc[4][4] = {};
    for (int kk = 0; kk < CH; kk += BK) {
#pragma unroll
        for (int i = 0; i < 2; ++i) {
            int slot = tid + i * 256;
            int row = slot >> 2, k8 = (slot & 3) << 3;
            *(uint4*)(As + row * LDK + k8) = *(const uint4*)(xb + (size_t)(m0 + row) * CH + kk + k8);
        }
#pragma unroll
        for (int i = 0; i < 2; ++i) {
            int slot = tid + i * 256;
            int row = slot >> 2, k8 = (slot & 3) << 3;
            *(uint4*)(Bs + row * LDK + k8) = *(const uint4*)(Wt + (size_t)(n0 + row) * CH + kk + k8);
        }
        __syncthreads();
        bf16x8 a[4], b[4];
#pragma unroll
        for (int r = 0; r < 4; ++r)
            a[r] = *(const bf16x8*)(As + (wm + r * 16 + l16) * LDK + quad * 8);
#pragma unroll
        for (int c = 0; c < 4; ++c)
            b[c] = *(const bf16x8*)(Bs + (wn + c * 16 + l16) * LDK + quad * 8);
#pragma unroll
        for (int r = 0; r < 4; ++r)
#pragma unroll
            for (int c = 0; c < 4; ++c)
                acc[r][c] = __builtin_amdgcn_mfma_f32_16x16x32_bf16(a[r], b[c], acc[r][c], 0, 0, 0);
        __syncthreads();
    }
#pragma unroll
    for (int r = 0; r < 4; ++r)
#pragma unroll
        for (int c = 0; c < 4; ++c) {
            int col = n0 + wn + c * 16 + l16;
            float bv = bias[col];
#pragma unroll
            for (int reg = 0; reg < 4; ++reg) {
                int row = m0 + wm + r * 16 + quad * 4 + reg;
                out[(size_t)row * CH + col] = f2bf(acc[r][c][reg] + bv);
            }
        }
}

// ---------------------------------------------------------------------------
// logits: E[b,t,s] = exp(q·k * INVSQ) for s<=t else 0 (bf16), Z[b,s] += colsum.
// grid (st=16, tt=16, b=8); early-out st>tt.
// ---------------------------------------------------------------------------
__global__ __launch_bounds__(256) void logits_kernel(
    const unsigned short* __restrict__ qb, const unsigned short* __restrict__ kb,
    unsigned short* __restrict__ E, float* __restrict__ Z)
{
    const int st = blockIdx.x, tt = blockIdx.y, b = blockIdx.z;
    if (st > tt) return;
    __shared__ unsigned short As[BM * LDK];
    __shared__ unsigned short Bs[BN * LDK];
    __shared__ float colsum[BN];
    const int m0 = tt * BM;   // t rows
    const int n0 = st * BN;   // s cols
    const int tid = threadIdx.x;
    const int lane = tid & 63, wave = tid >> 6;
    const int wm = (wave >> 1) * 64, wn = (wave & 1) * 64;
    const int quad = lane >> 4, l16 = lane & 15;
    const unsigned short* q = qb + (size_t)b * SEQ * CH;
    const unsigned short* k = kb + (size_t)b * SEQ * CH;

    f32x4 acc[4][4] = {};
    for (int kk = 0; kk < CH; kk += BK) {
#pragma unroll
        for (int i = 0; i < 2; ++i) {
            int slot = tid + i * 256;
            int row = slot >> 2, k8 = (slot & 3) << 3;
            *(uint4*)(As + row * LDK + k8) = *(const uint4*)(q + (size_t)(m0 + row) * CH + kk + k8);
        }
#pragma unroll
        for (int i = 0; i < 2; ++i) {
            int slot = tid + i * 256;
            int row = slot >> 2, k8 = (slot & 3) << 3;
            *(uint4*)(Bs + row * LDK + k8) = *(const uint4*)(k + (size_t)(n0 + row) * CH + kk + k8);
        }
        __syncthreads();
        bf16x8 a[4], bfr[4];
#pragma unroll
        for (int r = 0; r < 4; ++r)
            a[r] = *(const bf16x8*)(As + (wm + r * 16 + l16) * LDK + quad * 8);
#pragma unroll
        for (int c = 0; c < 4; ++c)
            bfr[c] = *(const bf16x8*)(Bs + (wn + c * 16 + l16) * LDK + quad * 8);
#pragma unroll
        for (int r = 0; r < 4; ++r)
#pragma unroll
            for (int c = 0; c < 4; ++c)
                acc[r][c] = __builtin_amdgcn_mfma_f32_16x16x32_bf16(a[r], bfr[c], acc[r][c], 0, 0, 0);
        __syncthreads();
    }
    if (tid < BN) colsum[tid] = 0.f;
    __syncthreads();
#pragma unroll
    for (int r = 0; r < 4; ++r)
#pragma unroll
        for (int c = 0; c < 4; ++c) {
            int cl = wn + c * 16 + l16;
            int s = n0 + cl;
            float csum = 0.f;
#pragma unroll
            for (int reg = 0; reg < 4; ++reg) {
                int t = m0 + wm + r * 16 + quad * 4 + reg;
                float e = (s <= t) ? __expf(acc[r][c][reg] * INVSQ) : 0.f;
                csum += e;
                E[((size_t)b * SEQ + t) * SEQ + s] = f2bf(e);
            }
            atomicAdd(&colsum[cl], csum);
        }
    __syncthreads();
    if (tid < BN) atomicAdd(&Z[b * SEQ + n0 + tid], colsum[tid]);
}

__global__ __launch_bounds__(256) void zero_kernel(float* __restrict__ Z) {
    int i = blockIdx.x * 256 + threadIdx.x;
    if (i < ROWS) Z[i] = 0.f;
}

// ---------------------------------------------------------------------------
// read = E @ Vt^T (causal K-loop), fp32 -> out[:, :, 512:1024]
// 1D grid 512, swizzled so co-resident pairs (id, id+256) get tt and 15-tt.
// ---------------------------------------------------------------------------
__global__ __launch_bounds__(256) void read_kernel(
    const unsigned short* __restrict__ E, const unsigned short* __restrict__ Vt,
    float* __restrict__ out)
{
    __shared__ unsigned short As[BM * LDK];
    __shared__ unsigned short Bs[BN * LDK];
    const int id = blockIdx.x;
    const int b = id & 7;
    const int rem = id >> 3;
    const int n = rem & 3;
    const int r0 = rem >> 2;                 // 0..15
    const int tt = (r0 < 8) ? r0 : 23 - r0;  // pairs (r0, r0+8) -> tt sums to 15
    const int n0 = n * BN;
    const int m0 = tt * BM;
    const int Kmax = (tt + 1) * BM;
    const int tid = threadIdx.x;
    const int lane = tid & 63, wave = tid >> 6;
    const int wm = (wave >> 1) * 64, wn = (wave & 1) * 64;
    const int quad = lane >> 4, l16 = lane & 15;
    const unsigned short* Eb = E + (size_t)b * SEQ * SEQ;
    const unsigned short* Vb = Vt + (size_t)b * CH * SEQ;   // [v][s]

    f32x4 acc[4][4] = {};
    for (int kk = 0; kk < Kmax; kk += BK) {
#pragma unroll
        for (int i = 0; i < 2; ++i) {
            int slot = tid + i * 256;
            int row = slot >> 2, k8 = (slot & 3) << 3;
            *(uint4*)(As + row * LDK + k8) = *(const uint4*)(Eb + (size_t)(m0 + row) * SEQ + kk + k8);
        }
#pragma unroll
        for (int i = 0; i < 2; ++i) {
            int slot = tid + i * 256;
            int row = slot >> 2, k8 = (slot & 3) << 3;
            *(uint4*)(Bs + row * LDK + k8) = *(const uint4*)(Vb + (size_t)(n0 + row) * SEQ + kk + k8);
        }
        __syncthreads();
        bf16x8 a[4], bfr[4];
#pragma unroll
        for (int r = 0; r < 4; ++r)
            a[r] = *(const bf16x8*)(As + (wm + r * 16 + l16) * LDK + quad * 8);
#pragma unroll
        for (int c = 0; c < 4; ++c)
            bfr[c] = *(const bf16x8*)(Bs + (wn + c * 16 + l16) * LDK + quad * 8);
#pragma unroll
        for (int r = 0; r < 4; ++r)
#pragma unroll
            for (int c = 0; c < 4; ++c)
                acc[r][c] = __builtin_amdgcn_mfma_f32_16x16x32_bf16(a[r], bfr[c], acc[r][c], 0, 0, 0);
        __syncthreads();
    }
    float* ob = out + ((size_t)b * SEQ + m0) * 1024 + 512 + n0;
#pragma unroll
    for (int r = 0; r < 4; ++r)
#pragma unroll
        for (int c = 0; c < 4; ++c)
#pragma unroll
            for (int reg = 0; reg < 4; ++reg)
                ob[(size_t)(wm + r * 16 + quad * 4 + reg) * 1024 + wn + c * 16 + l16] = acc[r][c][reg];
}

// ---------------------------------------------------------------------------
// copy x into out[:, :, 0:512]
// ---------------------------------------------------------------------------
__global__ __launch_bounds__(256) void copy_x_kernel(
    const float* __restrict__ x, float* __restrict__ out)
{
    int g = blockIdx.x * 256 + threadIdx.x;
    int row = g >> 7;
    int c4 = (g & 127) << 2;
    *(float4*)(out + (size_t)row * 1024 + c4) = *(const float4*)(x + (size_t)row * CH + c4);
}

extern "C" void kernel_launch(void* const* d_in, const int* in_sizes, int n_in,
                              void* d_out, int out_size, void* d_ws, size_t ws_size,
                              hipStream_t stream) {
    const float* x  = (const float*)d_in[0];
    const float* Wq = (const float*)d_in[1];
    const float* bq = (const float*)d_in[2];
    const float* Wk = (const float*)d_in[3];
    const float* bk = (const float*)d_in[4];
    const float* Wv = (const float*)d_in[5];
    const float* bv = (const float*)d_in[6];
    float* out = (float*)d_out;

    char* ws = (char*)d_ws;
    const size_t QKV_BYTES = (size_t)ROWS * CH * 2;              // 16,777,216
    const size_t E_BYTES   = (size_t)BATCH * SEQ * SEQ * 2;      // 67,108,864
    unsigned short* qb = (unsigned short*)ws;
    unsigned short* kb = (unsigned short*)(ws + QKV_BYTES);
    unsigned short* vb = (unsigned short*)(ws + 2 * QKV_BYTES);
    unsigned short* E  = (unsigned short*)(ws + 3 * QKV_BYTES);
    float* Z = (float*)(ws + 3 * QKV_BYTES + E_BYTES);
    // Aliases (lifetimes disjoint on the in-order stream):
    unsigned short* xb = E;                                       // dead before logits writes E
    unsigned short* Wt = (unsigned short*)((char*)E + QKV_BYTES); // dead before logits writes E
    unsigned short* Vt = qb;                                      // qb dead after logits

    dim3 blk(256);
    zero_kernel<<<dim3((ROWS + 255) / 256), blk, 0, stream>>>(Z);
    convert_x_kernel<<<dim3(4096), blk, 0, stream>>>(x, xb);
    transpose_w_kernel<<<dim3(8, 8, 3), blk, 0, stream>>>(Wq, Wk, Wv, Wt);
    qkv_kernel<<<dim3(4, 128), blk, 0, stream>>>(xb, Wt,               bq, qb);
    qkv_kernel<<<dim3(4, 128), blk, 0, stream>>>(xb, Wt + 1 * CH * CH, bk, kb);
    qkv_kernel<<<dim3(4, 128), blk, 0, stream>>>(xb, Wt + 2 * CH * CH, bv, vb);
    logits_kernel<<<dim3(16, 16, 8), blk, 0, stream>>>(qb, kb, E, Z);
    transpose_v_kernel<<<dim3(32, 8, 8), blk, 0, stream>>>(vb, Z, Vt);
    read_kernel<<<dim3(512), blk, 0, stream>>>(E, Vt, out);
    copy_x_kernel<<<dim3(8192), blk, 0, stream>>>(x, out);
}

// Round 3
// 267.452 us; speedup vs baseline: 1.9280x; 1.2088x over previous
//
#include <hip/hip_runtime.h>
#include <hip/hip_bf16.h>
#include <math.h>

// Problem constants
#define BATCH 8
#define SEQ   2048
#define CH    512
#define ROWS  (BATCH * SEQ)   // 16384
#define INVSQ 0.044194173824159216f  // 1/sqrt(512)

// GEMM tile config: 128x128 block tile, BK=32, unpadded LDS (global_load_lds)
#define BM 128
#define BK 32
#define TILE_ELEMS (BM * BK)   // 4096 bf16 = 8 KB
#define TP 68                  // transpose-tile pitch (2-way conflict = free)

typedef __attribute__((ext_vector_type(8))) __bf16 bf16x8;
typedef __attribute__((ext_vector_type(4))) float f32x4;

__device__ inline unsigned short f2bf(float f) {
    unsigned u = __builtin_bit_cast(unsigned, f);
    u += 0x7fffu + ((u >> 16) & 1u);   // round-to-nearest-even
    return (unsigned short)(u >> 16);
}
__device__ inline float bf2f(unsigned short s) {
    unsigned u = ((unsigned)s) << 16;
    return __builtin_bit_cast(float, u);
}

// Async-stage one 128x32 bf16 tile (8 KB) from global (row stride `stride`
// elems) into LDS. 4 waves x 2 chunks x 1 KB. LDS dest is wave-uniform base +
// lane*16 (HW rule), so layout is exactly row-major [128][32] unpadded.
__device__ __forceinline__ void stage_tile(
    const unsigned short* __restrict__ gbase, size_t stride,
    unsigned short* lds, int wave, int lane)
{
#pragma unroll
    for (int j = 0; j < 2; ++j) {
        int chunk = wave * 2 + j;                  // 0..7, 16 rows each
        int row = chunk * 16 + (lane >> 2);
        const unsigned short* g = gbase + (size_t)row * stride + ((lane & 3) << 3);
        __builtin_amdgcn_global_load_lds(
            (const __attribute__((address_space(1))) unsigned int*)g,
            (__attribute__((address_space(3))) unsigned int*)(lds + (chunk << 9)),
            16, 0, 0);
    }
}

// ---------------------------------------------------------------------------
// fuse_x: x fp32 [16384,512] -> out[:, :, 0:512] (fp32) AND xb (bf16).
// ---------------------------------------------------------------------------
__global__ __launch_bounds__(256) void fuse_x_kernel(
    const float* __restrict__ x, unsigned short* __restrict__ xb,
    float* __restrict__ out)
{
    size_t base = ((size_t)blockIdx.x * 256 + threadIdx.x) * 8;
    size_t row = base >> 9, c = base & 511;
    float4 v0 = *(const float4*)(x + base);
    float4 v1 = *(const float4*)(x + base + 4);
    float* o = out + row * 1024 + c;
    *(float4*)o = v0;
    *(float4*)(o + 4) = v1;
    alignas(16) unsigned short t[8];
    t[0] = f2bf(v0.x); t[1] = f2bf(v0.y); t[2] = f2bf(v0.z); t[3] = f2bf(v0.w);
    t[4] = f2bf(v1.x); t[5] = f2bf(v1.y); t[6] = f2bf(v1.z); t[7] = f2bf(v1.w);
    *(uint4*)(xb + base) = *(const uint4*)t;
}

// ---------------------------------------------------------------------------
// transpose_w: W fp32 [512 k][512 n] -> Wt bf16 [3][512 n][512 k]
// ---------------------------------------------------------------------------
__global__ __launch_bounds__(256) void transpose_w_kernel(
    const float* __restrict__ Wq, const float* __restrict__ Wk,
    const float* __restrict__ Wv, unsigned short* __restrict__ Wt)
{
    __shared__ unsigned short T[64 * TP];
    const int k0 = blockIdx.x * 64, n0 = blockIdx.y * 64, w = blockIdx.z;
    const float* W = (w == 0) ? Wq : (w == 1) ? Wk : Wv;
    const int tid = threadIdx.x;
#pragma unroll
    for (int i = 0; i < 2; ++i) {
        int slot = tid + i * 256;
        int kr = slot >> 3, c8 = (slot & 7) << 3;
        float4 a = *(const float4*)(W + (size_t)(k0 + kr) * CH + n0 + c8);
        float4 b = *(const float4*)(W + (size_t)(k0 + kr) * CH + n0 + c8 + 4);
        T[(c8 + 0) * TP + kr] = f2bf(a.x); T[(c8 + 1) * TP + kr] = f2bf(a.y);
        T[(c8 + 2) * TP + kr] = f2bf(a.z); T[(c8 + 3) * TP + kr] = f2bf(a.w);
        T[(c8 + 4) * TP + kr] = f2bf(b.x); T[(c8 + 5) * TP + kr] = f2bf(b.y);
        T[(c8 + 6) * TP + kr] = f2bf(b.z); T[(c8 + 7) * TP + kr] = f2bf(b.w);
    }
    __syncthreads();
#pragma unroll
    for (int i = 0; i < 2; ++i) {
        int slot = tid + i * 256;
        int nr = slot >> 3, k8 = (slot & 7) << 3;
        uint2 lo = *(const uint2*)(T + nr * TP + k8);
        uint2 hi = *(const uint2*)(T + nr * TP + k8 + 4);
        uint4 u; u.x = lo.x; u.y = lo.y; u.z = hi.x; u.w = hi.y;
        *(uint4*)(Wt + ((size_t)w * CH + n0 + nr) * CH + k0 + k8) = u;
    }
}

// ---------------------------------------------------------------------------
// transpose_v: vb bf16 [b][s][v] -> Vt bf16 [b][v][s], scaled by 1/Z[b][s].
// ---------------------------------------------------------------------------
__global__ __launch_bounds__(256) void transpose_v_kernel(
    const unsigned short* __restrict__ vb, const float* __restrict__ Z,
    unsigned short* __restrict__ Vt)
{
    __shared__ unsigned short T[64 * TP];
    const int s0 = blockIdx.x * 64, v0 = blockIdx.y * 64, b = blockIdx.z;
    const int tid = threadIdx.x;
#pragma unroll
    for (int i = 0; i < 2; ++i) {
        int slot = tid + i * 256;
        int sr = slot >> 3, c8 = (slot & 7) << 3;
        float inv = 1.0f / Z[b * SEQ + s0 + sr];
        uint4 raw = *(const uint4*)(vb + ((size_t)b * SEQ + s0 + sr) * CH + v0 + c8);
        const unsigned short* p = (const unsigned short*)&raw;
#pragma unroll
        for (int j = 0; j < 8; ++j)
            T[(c8 + j) * TP + sr] = f2bf(bf2f(p[j]) * inv);
    }
    __syncthreads();
#pragma unroll
    for (int i = 0; i < 2; ++i) {
        int slot = tid + i * 256;
        int vr = slot >> 3, s8 = (slot & 7) << 3;
        uint2 lo = *(const uint2*)(T + vr * TP + s8);
        uint2 hi = *(const uint2*)(T + vr * TP + s8 + 4);
        uint4 u; u.x = lo.x; u.y = lo.y; u.z = hi.x; u.w = hi.y;
        *(uint4*)(Vt + ((size_t)b * CH + v0 + vr) * SEQ + s0 + s8) = u;
    }
}

// ---------------------------------------------------------------------------
// qkv fused GEMM, swapped orientation: C[n(weight col), m(x row)].
// A = Wt [1536][512] k-major, B = xb [16384][512] k-major.
// grid (x-tiles=128, w-tiles=12). q gets INVSQ folded in.
// ---------------------------------------------------------------------------
__global__ __launch_bounds__(256) void qkv_kernel(
    const unsigned short* __restrict__ xb, const unsigned short* __restrict__ Wt,
    const float* __restrict__ bq, const float* __restrict__ bk,
    const float* __restrict__ bv, unsigned short* __restrict__ qkv)
{
    __shared__ unsigned short As[TILE_ELEMS];
    __shared__ unsigned short Bs[TILE_ELEMS];
    const int xrow0 = blockIdx.x * BM;
    const int wrow0 = blockIdx.y * BM;
    const int tid = threadIdx.x;
    const int lane = tid & 63, wave = tid >> 6;
    const int wm = (wave >> 1) * 64, wn = (wave & 1) * 64;
    const int quad = lane >> 4, l16 = lane & 15;

    f32x4 acc[4][4] = {};
    for (int kk = 0; kk < CH; kk += BK) {
        stage_tile(Wt + (size_t)wrow0 * CH + kk, CH, As, wave, lane);
        stage_tile(xb + (size_t)xrow0 * CH + kk, CH, Bs, wave, lane);
        __syncthreads();
        bf16x8 a[4], bb[4];
#pragma unroll
        for (int r = 0; r < 4; ++r)
            a[r] = *(const bf16x8*)(As + (wm + r * 16 + l16) * BK + quad * 8);
#pragma unroll
        for (int c = 0; c < 4; ++c)
            bb[c] = *(const bf16x8*)(Bs + (wn + c * 16 + l16) * BK + quad * 8);
#pragma unroll
        for (int r = 0; r < 4; ++r)
#pragma unroll
            for (int c = 0; c < 4; ++c)
                acc[r][c] = __builtin_amdgcn_mfma_f32_16x16x32_bf16(a[r], bb[c], acc[r][c], 0, 0, 0);
        __syncthreads();
    }
    const int which = wrow0 >> 9;   // uniform per block
    const float* bias = (which == 0) ? bq : (which == 1) ? bk : bv;
    const float scale = (which == 0) ? INVSQ : 1.0f;
    unsigned short* outw = qkv + (size_t)which * ROWS * CH;
    const int colblk = wrow0 & 511;
#pragma unroll
    for (int r = 0; r < 4; ++r) {
        int colb = colblk + wm + r * 16 + quad * 4;
        float4 b4 = *(const float4*)(bias + colb);
#pragma unroll
        for (int c = 0; c < 4; ++c) {
            int m = xrow0 + wn + c * 16 + l16;
            alignas(8) unsigned short pk[4];
            pk[0] = f2bf((acc[r][c][0] + b4.x) * scale);
            pk[1] = f2bf((acc[r][c][1] + b4.y) * scale);
            pk[2] = f2bf((acc[r][c][2] + b4.z) * scale);
            pk[3] = f2bf((acc[r][c][3] + b4.w) * scale);
            *(uint2*)(outw + (size_t)m * CH + colb) = *(const uint2*)pk;
        }
    }
}

// ---------------------------------------------------------------------------
// logits, swapped: C[s][t] = k_s . q_t (q pre-scaled by INVSQ).
// E[t][s] = exp(C) if s<=t else 0, packed 4-wide in s. Z[s] via shuffle+atomic.
// grid (st=16, tt=16, b=8); early-out st>tt.
// ---------------------------------------------------------------------------
__global__ __launch_bounds__(256) void logits_kernel(
    const unsigned short* __restrict__ qb, const unsigned short* __restrict__ kb,
    unsigned short* __restrict__ E, float* __restrict__ Z)
{
    const int st = blockIdx.x, tt = blockIdx.y, b = blockIdx.z;
    if (st > tt) return;
    __shared__ unsigned short As[TILE_ELEMS];
    __shared__ unsigned short Bs[TILE_ELEMS];
    const int m0s = st * BM;   // s rows (M dim, from k)
    const int n0t = tt * BM;   // t cols (N dim, from q)
    const int tid = threadIdx.x;
    const int lane = tid & 63, wave = tid >> 6;
    const int wm = (wave >> 1) * 64, wn = (wave & 1) * 64;
    const int quad = lane >> 4, l16 = lane & 15;
    const unsigned short* kB = kb + (size_t)b * SEQ * CH;
    const unsigned short* qB = qb + (size_t)b * SEQ * CH;

    f32x4 acc[4][4] = {};
    for (int kk = 0; kk < CH; kk += BK) {
        stage_tile(kB + (size_t)m0s * CH + kk, CH, As, wave, lane);
        stage_tile(qB + (size_t)n0t * CH + kk, CH, Bs, wave, lane);
        __syncthreads();
        bf16x8 a[4], bb[4];
#pragma unroll
        for (int r = 0; r < 4; ++r)
            a[r] = *(const bf16x8*)(As + (wm + r * 16 + l16) * BK + quad * 8);
#pragma unroll
        for (int c = 0; c < 4; ++c)
            bb[c] = *(const bf16x8*)(Bs + (wn + c * 16 + l16) * BK + quad * 8);
#pragma unroll
        for (int r = 0; r < 4; ++r)
#pragma unroll
            for (int c = 0; c < 4; ++c)
                acc[r][c] = __builtin_amdgcn_mfma_f32_16x16x32_bf16(a[r], bb[c], acc[r][c], 0, 0, 0);
        __syncthreads();
    }
#pragma unroll
    for (int r = 0; r < 4; ++r) {
        int sb = m0s + wm + r * 16 + quad * 4;
        float ev[4][4];
#pragma unroll
        for (int c = 0; c < 4; ++c) {
            int t = n0t + wn + c * 16 + l16;
#pragma unroll
            for (int reg = 0; reg < 4; ++reg)
                ev[c][reg] = (sb + reg <= t) ? __expf(acc[r][c][reg]) : 0.f;
        }
#pragma unroll
        for (int reg = 0; reg < 4; ++reg) {
            float z = ev[0][reg] + ev[1][reg] + ev[2][reg] + ev[3][reg];
            z += __shfl_xor(z, 1);
            z += __shfl_xor(z, 2);
            z += __shfl_xor(z, 4);
            z += __shfl_xor(z, 8);
            if (l16 == 0) atomicAdd(&Z[b * SEQ + sb + reg], z);
        }
#pragma unroll
        for (int c = 0; c < 4; ++c) {
            int t = n0t + wn + c * 16 + l16;
            alignas(8) unsigned short pk[4];
            pk[0] = f2bf(ev[c][0]); pk[1] = f2bf(ev[c][1]);
            pk[2] = f2bf(ev[c][2]); pk[3] = f2bf(ev[c][3]);
            *(uint2*)(E + ((size_t)b * SEQ + t) * SEQ + sb) = *(const uint2*)pk;
        }
    }
}

__global__ __launch_bounds__(256) void zero_kernel(float* __restrict__ Z) {
    int i = blockIdx.x * 256 + threadIdx.x;
    if (i < ROWS) Z[i] = 0.f;
}

// ---------------------------------------------------------------------------
// read, swapped: C[v][t] = sum_s Vt[v][s] * E[t][s] (causal K-loop).
// A = Vt [b][v][s], B = E [b][t][s]. fp32 packed float4 -> out[:, :, 512+v].
// 1D grid 512, tt balance-swizzled.
// ---------------------------------------------------------------------------
__global__ __launch_bounds__(256) void read_kernel(
    const unsigned short* __restrict__ E, const unsigned short* __restrict__ Vt,
    float* __restrict__ out)
{
    __shared__ unsigned short As[TILE_ELEMS];
    __shared__ unsigned short Bs[TILE_ELEMS];
    const int id = blockIdx.x;
    const int b = id & 7;
    const int rem = id >> 3;
    const int mv = rem & 3;                  // v tile (4)
    const int r0 = rem >> 2;                 // 0..15
    const int tt = (r0 < 8) ? r0 : 23 - r0;  // pairs (r0, r0+8) -> tt sums to 15
    const int m0v = mv * BM;
    const int n0t = tt * BM;
    const int Kmax = (tt + 1) * BM;
    const int tid = threadIdx.x;
    const int lane = tid & 63, wave = tid >> 6;
    const int wm = (wave >> 1) * 64, wn = (wave & 1) * 64;
    const int quad = lane >> 4, l16 = lane & 15;
    const unsigned short* Vb = Vt + (size_t)b * CH * SEQ;   // [v][s]
    const unsigned short* Eb = E + (size_t)b * SEQ * SEQ;   // [t][s]

    f32x4 acc[4][4] = {};
    for (int kk = 0; kk < Kmax; kk += BK) {
        stage_tile(Vb + (size_t)m0v * SEQ + kk, SEQ, As, wave, lane);
        stage_tile(Eb + (size_t)n0t * SEQ + kk, SEQ, Bs, wave, lane);
        __syncthreads();
        bf16x8 a[4], bb[4];
#pragma unroll
        for (int r = 0; r < 4; ++r)
            a[r] = *(const bf16x8*)(As + (wm + r * 16 + l16) * BK + quad * 8);
#pragma unroll
        for (int c = 0; c < 4; ++c)
            bb[c] = *(const bf16x8*)(Bs + (wn + c * 16 + l16) * BK + quad * 8);
#pragma unroll
        for (int r = 0; r < 4; ++r)
#pragma unroll
            for (int c = 0; c < 4; ++c)
                acc[r][c] = __builtin_amdgcn_mfma_f32_16x16x32_bf16(a[r], bb[c], acc[r][c], 0, 0, 0);
        __syncthreads();
    }
#pragma unroll
    for (int r = 0; r < 4; ++r) {
        int v = 512 + m0v + wm + r * 16 + quad * 4;
#pragma unroll
        for (int c = 0; c < 4; ++c) {
            int t = n0t + wn + c * 16 + l16;
            float4 f;
            f.x = acc[r][c][0]; f.y = acc[r][c][1];
            f.z = acc[r][c][2]; f.w = acc[r][c][3];
            *(float4*)(out + ((size_t)b * SEQ + t) * 1024 + v) = f;
        }
    }
}

extern "C" void kernel_launch(void* const* d_in, const int* in_sizes, int n_in,
                              void* d_out, int out_size, void* d_ws, size_t ws_size,
                              hipStream_t stream) {
    const float* x  = (const float*)d_in[0];
    const float* Wq = (const float*)d_in[1];
    const float* bq = (const float*)d_in[2];
    const float* Wk = (const float*)d_in[3];
    const float* bk = (const float*)d_in[4];
    const float* Wv = (const float*)d_in[5];
    const float* bv = (const float*)d_in[6];
    float* out = (float*)d_out;

    char* ws = (char*)d_ws;
    const size_t QKV_BYTES = (size_t)ROWS * CH * 2;              // 16,777,216
    const size_t E_BYTES   = (size_t)BATCH * SEQ * SEQ * 2;      // 67,108,864
    unsigned short* qkv = (unsigned short*)ws;                   // q,k,v contiguous
    unsigned short* qb = qkv;
    unsigned short* kb = (unsigned short*)(ws + QKV_BYTES);
    unsigned short* vb = (unsigned short*)(ws + 2 * QKV_BYTES);
    unsigned short* E  = (unsigned short*)(ws + 3 * QKV_BYTES);
    float* Z = (float*)(ws + 3 * QKV_BYTES + E_BYTES);
    // Aliases (lifetimes disjoint on the in-order stream):
    unsigned short* xb = E;                                       // dead before logits writes E
    unsigned short* Wt = (unsigned short*)((char*)E + QKV_BYTES); // dead before logits writes E
    unsigned short* Vt = qb;                                      // qb dead after logits

    dim3 blk(256);
    zero_kernel<<<dim3((ROWS + 255) / 256), blk, 0, stream>>>(Z);
    fuse_x_kernel<<<dim3(4096), blk, 0, stream>>>(x, xb, out);
    transpose_w_kernel<<<dim3(8, 8, 3), blk, 0, stream>>>(Wq, Wk, Wv, Wt);
    qkv_kernel<<<dim3(128, 12), blk, 0, stream>>>(xb, Wt, bq, bk, bv, qkv);
    logits_kernel<<<dim3(16, 16, 8), blk, 0, stream>>>(qb, kb, E, Z);
    transpose_v_kernel<<<dim3(32, 8, 8), blk, 0, stream>>>(vb, Z, Vt);
    read_kernel<<<dim3(512), blk, 0, stream>>>(E, Vt, out);
}

// Round 4
// 238.220 us; speedup vs baseline: 2.1646x; 1.1227x over previous
//
#include <hip/hip_runtime.h>
#include <hip/hip_bf16.h>
#include <math.h>

// Problem constants
#define BATCH 8
#define SEQ   2048
#define CH    512
#define ROWS  (BATCH * SEQ)   // 16384
#define INVSQ 0.044194173824159216f  // 1/sqrt(512)

// GEMM tile config: 128x128 block tile, K-step 64 as two 128x32 sub-tiles
#define BM 128
#define BK 32
#define TILE_ELEMS (BM * BK)   // 4096 bf16 = 8 KB (one sub-tile)
#define TP 68                  // transpose-tile pitch (2-way conflict = free)

typedef __attribute__((ext_vector_type(8))) __bf16 bf16x8;
typedef __attribute__((ext_vector_type(4))) float f32x4;

__device__ inline unsigned short f2bf(float f) {
    unsigned u = __builtin_bit_cast(unsigned, f);
    u += 0x7fffu + ((u >> 16) & 1u);   // round-to-nearest-even
    return (unsigned short)(u >> 16);
}
__device__ inline float bf2f(unsigned short s) {
    unsigned u = ((unsigned)s) << 16;
    return __builtin_bit_cast(float, u);
}

// Async-stage one 128x32 bf16 sub-tile (8 KB) from global (row stride `stride`
// elems) into LDS. Layout: row-major [128][32] unpadded (64 B rows -> 2-way
// bank aliasing on ds_read_b128 = free).
__device__ __forceinline__ void stage_tile(
    const unsigned short* __restrict__ gbase, size_t stride,
    unsigned short* lds, int wave, int lane)
{
#pragma unroll
    for (int j = 0; j < 2; ++j) {
        int chunk = wave * 2 + j;                  // 0..7, 16 rows each
        int row = chunk * 16 + (lane >> 2);
        const unsigned short* g = gbase + (size_t)row * stride + ((lane & 3) << 3);
        __builtin_amdgcn_global_load_lds(
            (const __attribute__((address_space(1))) unsigned int*)g,
            (__attribute__((address_space(3))) unsigned int*)(lds + (chunk << 9)),
            16, 0, 0);
    }
}

// Load a 64-row x 32-k fragment set (4x bf16x8) from a 128x32 sub-tile.
__device__ __forceinline__ void load_frags(
    const unsigned short* lds, int w0, int l16, int quad, bf16x8* f)
{
#pragma unroll
    for (int r = 0; r < 4; ++r)
        f[r] = *(const bf16x8*)(lds + (w0 + r * 16 + l16) * BK + quad * 8);
}

// ---------------------------------------------------------------------------
// fuse_x: x fp32 [16384,512] -> out[:, :, 0:512] (fp32) AND xb (bf16).
// Also zeroes Z (blocks 0..63).
// ---------------------------------------------------------------------------
__global__ __launch_bounds__(256) void fuse_x_kernel(
    const float* __restrict__ x, unsigned short* __restrict__ xb,
    float* __restrict__ out, float* __restrict__ Z)
{
    if (blockIdx.x < 64) Z[blockIdx.x * 256 + threadIdx.x] = 0.f;
    size_t base = ((size_t)blockIdx.x * 256 + threadIdx.x) * 8;
    size_t row = base >> 9, c = base & 511;
    float4 v0 = *(const float4*)(x + base);
    float4 v1 = *(const float4*)(x + base + 4);
    float* o = out + row * 1024 + c;
    *(float4*)o = v0;
    *(float4*)(o + 4) = v1;
    alignas(16) unsigned short t[8];
    t[0] = f2bf(v0.x); t[1] = f2bf(v0.y); t[2] = f2bf(v0.z); t[3] = f2bf(v0.w);
    t[4] = f2bf(v1.x); t[5] = f2bf(v1.y); t[6] = f2bf(v1.z); t[7] = f2bf(v1.w);
    *(uint4*)(xb + base) = *(const uint4*)t;
}

// ---------------------------------------------------------------------------
// transpose_w: W fp32 [512 k][512 n] -> Wt bf16 [3][512 n][512 k]
// ---------------------------------------------------------------------------
__global__ __launch_bounds__(256) void transpose_w_kernel(
    const float* __restrict__ Wq, const float* __restrict__ Wk,
    const float* __restrict__ Wv, unsigned short* __restrict__ Wt)
{
    __shared__ unsigned short T[64 * TP];
    const int k0 = blockIdx.x * 64, n0 = blockIdx.y * 64, w = blockIdx.z;
    const float* W = (w == 0) ? Wq : (w == 1) ? Wk : Wv;
    const int tid = threadIdx.x;
#pragma unroll
    for (int i = 0; i < 2; ++i) {
        int slot = tid + i * 256;
        int kr = slot >> 3, c8 = (slot & 7) << 3;
        float4 a = *(const float4*)(W + (size_t)(k0 + kr) * CH + n0 + c8);
        float4 b = *(const float4*)(W + (size_t)(k0 + kr) * CH + n0 + c8 + 4);
        T[(c8 + 0) * TP + kr] = f2bf(a.x); T[(c8 + 1) * TP + kr] = f2bf(a.y);
        T[(c8 + 2) * TP + kr] = f2bf(a.z); T[(c8 + 3) * TP + kr] = f2bf(a.w);
        T[(c8 + 4) * TP + kr] = f2bf(b.x); T[(c8 + 5) * TP + kr] = f2bf(b.y);
        T[(c8 + 6) * TP + kr] = f2bf(b.z); T[(c8 + 7) * TP + kr] = f2bf(b.w);
    }
    __syncthreads();
#pragma unroll
    for (int i = 0; i < 2; ++i) {
        int slot = tid + i * 256;
        int nr = slot >> 3, k8 = (slot & 7) << 3;
        uint2 lo = *(const uint2*)(T + nr * TP + k8);
        uint2 hi = *(const uint2*)(T + nr * TP + k8 + 4);
        uint4 u; u.x = lo.x; u.y = lo.y; u.z = hi.x; u.w = hi.y;
        *(uint4*)(Wt + ((size_t)w * CH + n0 + nr) * CH + k0 + k8) = u;
    }
}

// ---------------------------------------------------------------------------
// transpose_v: vb bf16 [b][s][v] -> Vt bf16 [b][v][s], scaled by 1/Z[b][s].
// ---------------------------------------------------------------------------
__global__ __launch_bounds__(256) void transpose_v_kernel(
    const unsigned short* __restrict__ vb, const float* __restrict__ Z,
    unsigned short* __restrict__ Vt)
{
    __shared__ unsigned short T[64 * TP];
    const int s0 = blockIdx.x * 64, v0 = blockIdx.y * 64, b = blockIdx.z;
    const int tid = threadIdx.x;
#pragma unroll
    for (int i = 0; i < 2; ++i) {
        int slot = tid + i * 256;
        int sr = slot >> 3, c8 = (slot & 7) << 3;
        float inv = 1.0f / Z[b * SEQ + s0 + sr];
        uint4 raw = *(const uint4*)(vb + ((size_t)b * SEQ + s0 + sr) * CH + v0 + c8);
        const unsigned short* p = (const unsigned short*)&raw;
#pragma unroll
        for (int j = 0; j < 8; ++j)
            T[(c8 + j) * TP + sr] = f2bf(bf2f(p[j]) * inv);
    }
    __syncthreads();
#pragma unroll
    for (int i = 0; i < 2; ++i) {
        int slot = tid + i * 256;
        int vr = slot >> 3, s8 = (slot & 7) << 3;
        uint2 lo = *(const uint2*)(T + vr * TP + s8);
        uint2 hi = *(const uint2*)(T + vr * TP + s8 + 4);
        uint4 u; u.x = lo.x; u.y = lo.y; u.z = hi.x; u.w = hi.y;
        *(uint4*)(Vt + ((size_t)b * CH + v0 + vr) * SEQ + s0 + s8) = u;
    }
}

// ---------------------------------------------------------------------------
// qkv fused GEMM, swapped orientation: C[n(weight col), m(x row)].
// A = Wt [1536][512] k-major, B = xb [16384][512] k-major.
// grid (x-tiles=128, w-tiles=12). q gets INVSQ folded in. BK=64 (2 sub-tiles).
// ---------------------------------------------------------------------------
__global__ __launch_bounds__(256) void qkv_kernel(
    const unsigned short* __restrict__ xb, const unsigned short* __restrict__ Wt,
    const float* __restrict__ bq, const float* __restrict__ bk,
    const float* __restrict__ bv, unsigned short* __restrict__ qkv)
{
    __shared__ unsigned short As[2 * TILE_ELEMS];
    __shared__ unsigned short Bs[2 * TILE_ELEMS];
    const int xrow0 = blockIdx.x * BM;
    const int wrow0 = blockIdx.y * BM;
    const int tid = threadIdx.x;
    const int lane = tid & 63, wave = tid >> 6;
    const int wm = (wave >> 1) * 64, wn = (wave & 1) * 64;
    const int quad = lane >> 4, l16 = lane & 15;

    f32x4 acc[4][4] = {};
    for (int kk = 0; kk < CH; kk += 64) {
        stage_tile(Wt + (size_t)wrow0 * CH + kk,      CH, As,              wave, lane);
        stage_tile(Wt + (size_t)wrow0 * CH + kk + 32, CH, As + TILE_ELEMS, wave, lane);
        stage_tile(xb + (size_t)xrow0 * CH + kk,      CH, Bs,              wave, lane);
        stage_tile(xb + (size_t)xrow0 * CH + kk + 32, CH, Bs + TILE_ELEMS, wave, lane);
        __syncthreads();
#pragma unroll
        for (int h = 0; h < 2; ++h) {
            bf16x8 a[4], bb[4];
            load_frags(As + h * TILE_ELEMS, wm, l16, quad, a);
            load_frags(Bs + h * TILE_ELEMS, wn, l16, quad, bb);
#pragma unroll
            for (int r = 0; r < 4; ++r)
#pragma unroll
                for (int c = 0; c < 4; ++c)
                    acc[r][c] = __builtin_amdgcn_mfma_f32_16x16x32_bf16(a[r], bb[c], acc[r][c], 0, 0, 0);
        }
        __syncthreads();
    }
    const int which = wrow0 >> 9;   // uniform per block
    const float* bias = (which == 0) ? bq : (which == 1) ? bk : bv;
    const float scale = (which == 0) ? INVSQ : 1.0f;
    unsigned short* outw = qkv + (size_t)which * ROWS * CH;
    const int colblk = wrow0 & 511;
#pragma unroll
    for (int r = 0; r < 4; ++r) {
        int colb = colblk + wm + r * 16 + quad * 4;
        float4 b4 = *(const float4*)(bias + colb);
#pragma unroll
        for (int c = 0; c < 4; ++c) {
            int m = xrow0 + wn + c * 16 + l16;
            alignas(8) unsigned short pk[4];
            pk[0] = f2bf((acc[r][c][0] + b4.x) * scale);
            pk[1] = f2bf((acc[r][c][1] + b4.y) * scale);
            pk[2] = f2bf((acc[r][c][2] + b4.z) * scale);
            pk[3] = f2bf((acc[r][c][3] + b4.w) * scale);
            *(uint2*)(outw + (size_t)m * CH + colb) = *(const uint2*)pk;
        }
    }
}

// ---------------------------------------------------------------------------
// logits, swapped: C[s][t] = k_s . q_t (q pre-scaled by INVSQ).
// E[t][s] = exp(C) if s<=t else 0, packed 4-wide in s. Z[s] via shuffle+atomic.
// Compressed 1D grid: only the 136 live (st<=tt) pairs x 8 batches = 1088.
// ---------------------------------------------------------------------------
__global__ __launch_bounds__(256) void logits_kernel(
    const unsigned short* __restrict__ qb, const unsigned short* __restrict__ kb,
    unsigned short* __restrict__ E, float* __restrict__ Z)
{
    __shared__ unsigned short As[2 * TILE_ELEMS];
    __shared__ unsigned short Bs[2 * TILE_ELEMS];
    const int id = blockIdx.x;
    const int b = id & 7;
    const int i = id >> 3;                         // 0..135 triangle index
    int tt = (int)((sqrtf(8.f * (float)i + 1.f) - 1.f) * 0.5f);
    int st = i - ((tt * (tt + 1)) >> 1);
    while (st < 0)  { --tt; st = i - ((tt * (tt + 1)) >> 1); }
    while (st > tt) { ++tt; st = i - ((tt * (tt + 1)) >> 1); }
    const int m0s = st * BM;   // s rows (M dim, from k)
    const int n0t = tt * BM;   // t cols (N dim, from q)
    const int tid = threadIdx.x;
    const int lane = tid & 63, wave = tid >> 6;
    const int wm = (wave >> 1) * 64, wn = (wave & 1) * 64;
    const int quad = lane >> 4, l16 = lane & 15;
    const unsigned short* kB = kb + (size_t)b * SEQ * CH;
    const unsigned short* qB = qb + (size_t)b * SEQ * CH;

    f32x4 acc[4][4] = {};
    for (int kk = 0; kk < CH; kk += 64) {
        stage_tile(kB + (size_t)m0s * CH + kk,      CH, As,              wave, lane);
        stage_tile(kB + (size_t)m0s * CH + kk + 32, CH, As + TILE_ELEMS, wave, lane);
        stage_tile(qB + (size_t)n0t * CH + kk,      CH, Bs,              wave, lane);
        stage_tile(qB + (size_t)n0t * CH + kk + 32, CH, Bs + TILE_ELEMS, wave, lane);
        __syncthreads();
#pragma unroll
        for (int h = 0; h < 2; ++h) {
            bf16x8 a[4], bb[4];
            load_frags(As + h * TILE_ELEMS, wm, l16, quad, a);
            load_frags(Bs + h * TILE_ELEMS, wn, l16, quad, bb);
#pragma unroll
            for (int r = 0; r < 4; ++r)
#pragma unroll
                for (int c = 0; c < 4; ++c)
                    acc[r][c] = __builtin_amdgcn_mfma_f32_16x16x32_bf16(a[r], bb[c], acc[r][c], 0, 0, 0);
        }
        __syncthreads();
    }
#pragma unroll
    for (int r = 0; r < 4; ++r) {
        int sb = m0s + wm + r * 16 + quad * 4;
        float ev[4][4];
#pragma unroll
        for (int c = 0; c < 4; ++c) {
            int t = n0t + wn + c * 16 + l16;
#pragma unroll
            for (int reg = 0; reg < 4; ++reg)
                ev[c][reg] = (sb + reg <= t) ? __expf(acc[r][c][reg]) : 0.f;
        }
#pragma unroll
        for (int reg = 0; reg < 4; ++reg) {
            float z = ev[0][reg] + ev[1][reg] + ev[2][reg] + ev[3][reg];
            z += __shfl_xor(z, 1);
            z += __shfl_xor(z, 2);
            z += __shfl_xor(z, 4);
            z += __shfl_xor(z, 8);
            if (l16 == 0) atomicAdd(&Z[b * SEQ + sb + reg], z);
        }
#pragma unroll
        for (int c = 0; c < 4; ++c) {
            int t = n0t + wn + c * 16 + l16;
            alignas(8) unsigned short pk[4];
            pk[0] = f2bf(ev[c][0]); pk[1] = f2bf(ev[c][1]);
            pk[2] = f2bf(ev[c][2]); pk[3] = f2bf(ev[c][3]);
            *(uint2*)(E + ((size_t)b * SEQ + t) * SEQ + sb) = *(const uint2*)pk;
        }
    }
}

// ---------------------------------------------------------------------------
// read, swapped: C[v][t] = sum_s Vt[v][s] * E[t][s] (causal K-loop, BK=64).
// A = Vt [b][v][s], B = E [b][t][s]. fp32 packed float4 -> out[:, :, 512+v].
// 1D grid 512, tt balance-swizzled.
// ---------------------------------------------------------------------------
__global__ __launch_bounds__(256) void read_kernel(
    const unsigned short* __restrict__ E, const unsigned short* __restrict__ Vt,
    float* __restrict__ out)
{
    __shared__ unsigned short As[2 * TILE_ELEMS];
    __shared__ unsigned short Bs[2 * TILE_ELEMS];
    const int id = blockIdx.x;
    const int b = id & 7;
    const int rem = id >> 3;
    const int mv = rem & 3;                  // v tile (4)
    const int r0 = rem >> 2;                 // 0..15
    const int tt = (r0 < 8) ? r0 : 23 - r0;  // pairs (r0, r0+8) -> tt sums to 15
    const int m0v = mv * BM;
    const int n0t = tt * BM;
    const int Kmax = (tt + 1) * BM;
    const int tid = threadIdx.x;
    const int lane = tid & 63, wave = tid >> 6;
    const int wm = (wave >> 1) * 64, wn = (wave & 1) * 64;
    const int quad = lane >> 4, l16 = lane & 15;
    const unsigned short* Vb = Vt + (size_t)b * CH * SEQ;   // [v][s]
    const unsigned short* Eb = E + (size_t)b * SEQ * SEQ;   // [t][s]

    f32x4 acc[4][4] = {};
    for (int kk = 0; kk < Kmax; kk += 64) {
        stage_tile(Vb + (size_t)m0v * SEQ + kk,      SEQ, As,              wave, lane);
        stage_tile(Vb + (size_t)m0v * SEQ + kk + 32, SEQ, As + TILE_ELEMS, wave, lane);
        stage_tile(Eb + (size_t)n0t * SEQ + kk,      SEQ, Bs,              wave, lane);
        stage_tile(Eb + (size_t)n0t * SEQ + kk + 32, SEQ, Bs + TILE_ELEMS, wave, lane);
        __syncthreads();
#pragma unroll
        for (int h = 0; h < 2; ++h) {
            bf16x8 a[4], bb[4];
            load_frags(As + h * TILE_ELEMS, wm, l16, quad, a);
            load_frags(Bs + h * TILE_ELEMS, wn, l16, quad, bb);
#pragma unroll
            for (int r = 0; r < 4; ++r)
#pragma unroll
                for (int c = 0; c < 4; ++c)
                    acc[r][c] = __builtin_amdgcn_mfma_f32_16x16x32_bf16(a[r], bb[c], acc[r][c], 0, 0, 0);
        }
        __syncthreads();
    }
#pragma unroll
    for (int r = 0; r < 4; ++r) {
        int v = 512 + m0v + wm + r * 16 + quad * 4;
#pragma unroll
        for (int c = 0; c < 4; ++c) {
            int t = n0t + wn + c * 16 + l16;
            float4 f;
            f.x = acc[r][c][0]; f.y = acc[r][c][1];
            f.z = acc[r][c][2]; f.w = acc[r][c][3];
            *(float4*)(out + ((size_t)b * SEQ + t) * 1024 + v) = f;
        }
    }
}

extern "C" void kernel_launch(void* const* d_in, const int* in_sizes, int n_in,
                              void* d_out, int out_size, void* d_ws, size_t ws_size,
                              hipStream_t stream) {
    const float* x  = (const float*)d_in[0];
    const float* Wq = (const float*)d_in[1];
    const float* bq = (const float*)d_in[2];
    const float* Wk = (const float*)d_in[3];
    const float* bk = (const float*)d_in[4];
    const float* Wv = (const float*)d_in[5];
    const float* bv = (const float*)d_in[6];
    float* out = (float*)d_out;

    char* ws = (char*)d_ws;
    const size_t QKV_BYTES = (size_t)ROWS * CH * 2;              // 16,777,216
    const size_t E_BYTES   = (size_t)BATCH * SEQ * SEQ * 2;      // 67,108,864
    unsigned short* qkv = (unsigned short*)ws;                   // q,k,v contiguous
    unsigned short* qb = qkv;
    unsigned short* kb = (unsigned short*)(ws + QKV_BYTES);
    unsigned short* vb = (unsigned short*)(ws + 2 * QKV_BYTES);
    unsigned short* E  = (unsigned short*)(ws + 3 * QKV_BYTES);
    float* Z = (float*)(ws + 3 * QKV_BYTES + E_BYTES);
    // Aliases (lifetimes disjoint on the in-order stream):
    unsigned short* xb = E;                                       // dead before logits writes E
    unsigned short* Wt = (unsigned short*)((char*)E + QKV_BYTES); // dead before logits writes E
    unsigned short* Vt = qb;                                      // qb dead after logits

    dim3 blk(256);
    fuse_x_kernel<<<dim3(4096), blk, 0, stream>>>(x, xb, out, Z);
    transpose_w_kernel<<<dim3(8, 8, 3), blk, 0, stream>>>(Wq, Wk, Wv, Wt);
    qkv_kernel<<<dim3(128, 12), blk, 0, stream>>>(xb, Wt, bq, bk, bv, qkv);
    logits_kernel<<<dim3(1088), blk, 0, stream>>>(qb, kb, E, Z);
    transpose_v_kernel<<<dim3(32, 8, 8), blk, 0, stream>>>(vb, Z, Vt);
    read_kernel<<<dim3(512), blk, 0, stream>>>(E, Vt, out);
}